// Round 9
// baseline (199.550 us; speedup 1.0000x reference)
//
#include <hip/hip_runtime.h>
#include <stdint.h>

#define B_   8
#define KB_  16
#define SEQ_ 512
#define HID_ 768

#define NKB  (HID_ / 32)         // 24 k-blocks (32 halves each) per row
#define QRB  (B_  * SEQ_ / 16)   // 256 Q 16-row blocks
#define KRB  (KB_ * SEQ_ / 16)   // 512 K 16-row blocks

typedef __attribute__((ext_vector_type(4))) _Float16 half4;
typedef __attribute__((ext_vector_type(8))) _Float16 half8;
typedef __attribute__((ext_vector_type(4))) float    floatx4;

#define GLOBAL_AS __attribute__((address_space(1)))
#define LDS_AS    __attribute__((address_space(3)))

// async 16B/lane global->LDS copy: LDS dest = base + lane*16 (wave-uniform base);
// global source address may be fully per-lane.
static __device__ __forceinline__ void async_tile16(const _Float16* g, _Float16* l)
{
    __builtin_amdgcn_global_load_lds((const GLOBAL_AS uint32_t*)g,
                                     (LDS_AS uint32_t*)l, 16, 0, 0);
}

// ---------------- kernel 0: mask scan -> compaction maps + zero pad rows -------------
// 24 blocks (b<8: Q batch i=b; else K batch j=b-8) x 512 threads.
__global__ __launch_bounds__(512)
void scan_mask(const int* __restrict__ qmask, const int* __restrict__ kmask,
               int* __restrict__ pos_of, float* __restrict__ oidxf,
               int* __restrict__ nvalid,
               _Float16* __restrict__ Qc, _Float16* __restrict__ Kc)
{
    const int b   = blockIdx.x;
    const int tid = threadIdx.x;
    const int* m  = (b < 8) ? (qmask + b * SEQ_) : (kmask + (b - 8) * SEQ_);
    const int lane = tid & 63, wave = tid >> 6;

    int v = (m[tid] != 0) ? 1 : 0;
    int x = v;
#pragma unroll
    for (int off = 1; off < 64; off <<= 1) {
        int y = __shfl_up(x, off, 64);
        if (lane >= off) x += y;
    }
    __shared__ int wsum[8];
    __shared__ int nv_s;
    if (lane == 63) wsum[wave] = x;
    __syncthreads();
    int base = 0;
#pragma unroll
    for (int w = 0; w < 8; ++w) base += (w < wave) ? wsum[w] : 0;
    int incl = base + x;
    int pos  = incl - v;               // exclusive prefix
    pos_of[b * SEQ_ + tid] = v ? pos : -1;
    if (v) oidxf[b * SEQ_ + pos] = (float)tid;
    if (tid == 511) nv_s = incl;
    __syncthreads();
    int nv = nv_s;
    if (tid == 0) nvalid[b] = nv;
    if (tid >= nv) oidxf[b * SEQ_ + tid] = 0.f;   // de-poison pads

    // zero pad rows up to the 128-row tile boundary (keeps MFMA inputs NaN-free)
    int lim = (nv + 127) & ~127;
    if (lim > SEQ_) lim = SEQ_;
    _Float16* dstb = (b < 8) ? (Qc + (size_t)b * SEQ_ * HID_)
                             : (Kc + (size_t)(b - 8) * SEQ_ * HID_);
    for (int p = nv + tid; p < lim; p += 512) {
        _Float16* d = dstb + (size_t)p * HID_;
        half8 z = {0, 0, 0, 0, 0, 0, 0, 0};
#pragma unroll
        for (int c = 0; c < HID_ / 8; ++c) *(half8*)(d + c * 8) = z;
    }
}

// ---------------- kernel 1: L2-normalize valid rows -> compacted fp16 row-major ------
// one wave per source row; dead rows skipped (saves half the read BW).
__global__ __launch_bounds__(256)
void prep_norm(const float* __restrict__ Q, const float* __restrict__ K,
               const int* __restrict__ pos_of,
               _Float16* __restrict__ Qc, _Float16* __restrict__ Kc)
{
    const int rb = blockIdx.x;   // 0..767
    const float* src; _Float16* dstb; const int* pf;
    if (rb < QRB) {
        int i = rb >> 5;                       // 32 blocks per batch
        src  = Q + (size_t)rb * 16 * HID_;
        dstb = Qc + (size_t)i * SEQ_ * HID_;
        pf   = pos_of + i * SEQ_ + (rb & 31) * 16;
    } else {
        int rk = rb - QRB;
        int j  = rk >> 5;
        src  = K + (size_t)rk * 16 * HID_;
        dstb = Kc + (size_t)j * SEQ_ * HID_;
        pf   = pos_of + (8 + j) * SEQ_ + (rk & 31) * 16;
    }
    const int wave = threadIdx.x >> 6;
    const int lane = threadIdx.x & 63;

#pragma unroll
    for (int rr = 0; rr < 4; ++rr) {
        int row = wave * 4 + rr;
        int pos = pf[row];                     // wave-uniform
        if (pos < 0) continue;
        const float* s = src + (size_t)row * HID_;
        float4 v[3];
        float ss = 0.f;
#pragma unroll
        for (int it = 0; it < 3; ++it) {
            v[it] = *(const float4*)(s + lane * 4 + it * 256);
            ss += v[it].x * v[it].x + v[it].y * v[it].y + v[it].z * v[it].z + v[it].w * v[it].w;
        }
#pragma unroll
        for (int m = 1; m < 64; m <<= 1) ss += __shfl_xor(ss, m, 64);
        float sc = 1.0f / fmaxf(sqrtf(ss), 1e-12f);
        _Float16* d = dstb + (size_t)pos * HID_;
#pragma unroll
        for (int it = 0; it < 3; ++it) {
            half4 h = { (_Float16)(v[it].x * sc), (_Float16)(v[it].y * sc),
                        (_Float16)(v[it].z * sc), (_Float16)(v[it].w * sc) };
            *(half4*)(d + lane * 4 + it * 256) = h;
        }
    }
}

// ---------------- kernel 2: compacted 128x128-tile GEMM + sum-softmax partials -------
// grid (16, 16, 8) with early exit past valid tiles; 256 thr, 4 waves (2x2), 4 blk/CU.
__global__ __launch_bounds__(256, 4)
void li_part(const _Float16* __restrict__ Qc, const _Float16* __restrict__ Kc,
             const float* __restrict__ alpha_p, const int* __restrict__ nvalid,
             const float* __restrict__ oidxf, float* __restrict__ Pbuf)
{
    const int st = blockIdx.x >> 2;
    const int tb = blockIdx.x & 3;
    const int j  = blockIdx.y;
    const int i  = blockIdx.z;

    const int tid  = threadIdx.x;
    const int lane = tid & 63;
    const int wave = tid >> 6;
    const int quad = lane >> 4;
    const int l16  = lane & 15;
    const int wr   = wave >> 1;
    const int wc   = wave & 1;

    const int nvq = nvalid[i];
    const int nvk = nvalid[8 + j];
    const int stiles = (nvq + 127) >> 7;
    const int ttiles = (nvk + 127) >> 7;

    const size_t pbase0 = (((size_t)(i * KB_ + j) * SEQ_) + st * 128) * 8 + tb * 2;
    if (st >= stiles || tb >= ttiles) {        // dead tile: zero partials, exit
        if (tid < 128) {
            Pbuf[pbase0 + (size_t)tid * 8]     = 0.f;
            Pbuf[pbase0 + (size_t)tid * 8 + 1] = 0.f;
        }
        return;
    }

    __shared__ __align__(16) _Float16 smem[2 * 16 * 512];   // 32 KB double buffer
    __shared__ float lred[2][128], nred[2][128];

    const float araw  = *alpha_p;
    const float alpha = araw >= 0.f ? araw : 0.01f * araw;   // leaky_relu

    // staging: wave stages tiles wave*4..+3 (t<8: Q row-group, else K); per-lane source
    // addr = row-major compacted row (group*16 + (lane&15)), k-offset (lane>>4)*8.
    const _Float16* gsrc[4];
    _Float16*       ldst0[4];
#pragma unroll
    for (int q = 0; q < 4; ++q) {
        int t = wave * 4 + q;
        size_t row;
        const _Float16* basep;
        if (t < 8) { row = (size_t)i * SEQ_ + st * 128 + t * 16 + (lane & 15);       basep = Qc; }
        else       { row = (size_t)j * SEQ_ + tb * 128 + (t - 8) * 16 + (lane & 15); basep = Kc; }
        gsrc[q]  = basep + row * HID_ + (lane >> 4) * 8;
        ldst0[q] = &smem[t * 512];
    }

    floatx4 acc[4][4];
#pragma unroll
    for (int rt = 0; rt < 4; ++rt)
#pragma unroll
        for (int ct = 0; ct < 4; ++ct)
            acc[rt][ct] = (floatx4){0.f, 0.f, 0.f, 0.f};

#pragma unroll
    for (int q = 0; q < 4; ++q)
        async_tile16(gsrc[q], ldst0[q]);

    for (int kb = 0; kb < NKB; ++kb) {
        const int b = kb & 1;
        __syncthreads();
        if (kb + 1 < NKB) {
#pragma unroll
            for (int q = 0; q < 4; ++q)
                async_tile16(gsrc[q] + (size_t)(kb + 1) * 32, ldst0[q] + (b ^ 1) * 16 * 512);
        }
        const _Float16* Qs = &smem[b * 16 * 512];
        const _Float16* Ks = Qs + 8 * 512;
        half8 af[4], bf[4];
#pragma unroll
        for (int rt = 0; rt < 4; ++rt)
            af[rt] = *(const half8*)(Qs + (wr * 4 + rt) * 512 + lane * 8);
#pragma unroll
        for (int ct = 0; ct < 4; ++ct)
            bf[ct] = *(const half8*)(Ks + (wc * 4 + ct) * 512 + lane * 8);
#pragma unroll
        for (int rt = 0; rt < 4; ++rt)
#pragma unroll
            for (int ct = 0; ct < 4; ++ct)
                acc[rt][ct] = __builtin_amdgcn_mfma_f32_16x16x32_f16(af[rt], bf[ct], acc[rt][ct], 0, 0, 0);
    }

    // ---- epilogue: validity = compacted index < nvalid; distance from orig indices ----
    const float* tgfp = oidxf + (8 + j) * SEQ_ + tb * 128;
    const float* sgfp = oidxf + i * SEQ_ + st * 128;
    int kmv[4]; float tgf[4];
#pragma unroll
    for (int ct = 0; ct < 4; ++ct) {
        int t_loc = wc * 64 + ct * 16 + l16;
        kmv[ct] = (tb * 128 + t_loc) < nvk;
        tgf[ct] = tgfp[t_loc];
    }
#pragma unroll
    for (int rt = 0; rt < 4; ++rt) {
#pragma unroll
        for (int r = 0; r < 4; ++r) {
            int rloc = wr * 64 + rt * 16 + quad * 4 + r;
            float sgf = sgfp[rloc];
            float ps = 0.f, ns = 0.f;
#pragma unroll
            for (int ct = 0; ct < 4; ++ct) {
                float cv = acc[rt][ct][r];
                float e  = kmv[ct] ? __expf(cv * __expf(-alpha * fabsf(sgf - tgf[ct]))) : 0.f;
                ps += e;
                ns += e * cv;
            }
#pragma unroll
            for (int msk = 1; msk < 16; msk <<= 1) {
                ps += __shfl_xor(ps, msk, 64);
                ns += __shfl_xor(ns, msk, 64);
            }
            if (l16 == 0) {
                int valid_row = (st * 128 + rloc) < nvq;
                lred[wc][rloc] = valid_row ? ps : 0.f;
                nred[wc][rloc] = valid_row ? ns : 0.f;
            }
        }
    }
    __syncthreads();

    if (tid < 128) {
        Pbuf[pbase0 + (size_t)tid * 8]     = lred[0][tid] + lred[1][tid];
        Pbuf[pbase0 + (size_t)tid * 8 + 1] = nred[0][tid] + nred[1][tid];
    }
}

// ---------------- kernel 3: sum t-tile partials, reduce over compacted s -------------
__global__ __launch_bounds__(256)
void li_reduce(const float* __restrict__ Pbuf, float* __restrict__ out)
{
    const int ij  = blockIdx.x;
    const int tid = threadIdx.x;
    __shared__ float red[4];

    float sum = 0.f;
#pragma unroll
    for (int rep = 0; rep < 2; ++rep) {
        int s = tid + rep * 256;
        const float4* p = (const float4*)(Pbuf + ((size_t)ij * SEQ_ + s) * 8);
        float4 a = p[0], b = p[1];
        float l = a.x + a.z + b.x + b.z;
        float n = a.y + a.w + b.y + b.w;
        sum += (l > 0.f) ? n / l : 0.f;
    }
#pragma unroll
    for (int m = 1; m < 64; m <<= 1) sum += __shfl_xor(sum, m, 64);
    if ((tid & 63) == 0) red[tid >> 6] = sum;
    __syncthreads();
    if (tid == 0) out[ij] = red[0] + red[1] + red[2] + red[3];
}

extern "C" void kernel_launch(void* const* d_in, const int* in_sizes, int n_in,
                              void* d_out, int out_size, void* d_ws, size_t ws_size,
                              hipStream_t stream)
{
    const float* Q       = (const float*)d_in[0];
    const float* K       = (const float*)d_in[1];
    const float* alpha_p = (const float*)d_in[2];
    const int*   qmask   = (const int*)d_in[3];
    const int*   kmask   = (const int*)d_in[4];
    float*       out     = (float*)d_out;

    char* ws = (char*)d_ws;
    _Float16* Qc    = (_Float16*)ws;                                          // 6.3 MB
    _Float16* Kc    = (_Float16*)(ws + (size_t)B_ * SEQ_ * HID_ * 2);         // 12.6 MB
    float*    Pbuf  = (float*)   (ws + (size_t)(B_ + KB_) * SEQ_ * HID_ * 2); // 2 MB
    char*     ws2   = ws + (size_t)(B_ + KB_) * SEQ_ * HID_ * 2
                         + (size_t)B_ * KB_ * SEQ_ * 8 * sizeof(float);
    int*      pos_of = (int*)ws2;                          // 24*512 ints
    float*    oidxf  = (float*)(ws2 + 24 * SEQ_ * 4);      // 24*512 floats
    int*      nvalid = (int*)(ws2 + 2 * 24 * SEQ_ * 4);    // 24 ints

    scan_mask<<<24, 512, 0, stream>>>(qmask, kmask, pos_of, oidxf, nvalid, Qc, Kc);

    prep_norm<<<QRB + KRB, 256, 0, stream>>>(Q, K, pos_of, Qc, Kc);

    dim3 grid(16, KB_, B_);
    li_part<<<grid, 256, 0, stream>>>(Qc, Kc, alpha_p, nvalid, oidxf, Pbuf);

    li_reduce<<<B_ * KB_, 256, 0, stream>>>(Pbuf, out);
}